// Round 7
// baseline (232.643 us; speedup 1.0000x reference)
//
#include <hip/hip_runtime.h>
#include <hip/hip_fp16.h>
#include <math.h>

#define IN_DIM 256
#define HID 32
#define NSEG 100000
#define TROWS 64
#define ROWB 1024   // bytes per x-row (256 f32)

typedef _Float16 half8 __attribute__((ext_vector_type(8)));
typedef __fp16  fp16x2 __attribute__((ext_vector_type(2)));   // cvt_pkrtz return type
typedef float floatx4 __attribute__((ext_vector_type(4)));

// async global->LDS, 16B per lane, dest = wave-uniform base + lane*16 (m104)
__device__ __forceinline__ void gload_lds16(const float* g, char* l) {
    __builtin_amdgcn_global_load_lds(
        (const __attribute__((address_space(1))) void*)g,
        (__attribute__((address_space(3))) void*)l,
        16, 0, 0);
}

// Fused q/k projection (f16 MFMA, fp32 accum) + per-row dot + exp + segment-sum.
// Per block: 64-row x-tile staged via global_load_lds into 64KB LDS (linear dest,
// pre-swizzled source; read side applies the same XOR -> 2-way conflicts only).
// Loop is single-drain: stage_{i+1} and epilogue_i are issued together after the
// LDS-consumption barrier, and drained by ONE vmcnt(0) at top of next iteration,
// so the store+atomic latency hides under the next tile's HBM stream.
__global__ __launch_bounds__(256, 2) void att_kernel(
    const float* __restrict__ x,
    const float* __restrict__ Wq, const float* __restrict__ bq,
    const float* __restrict__ Wk, const float* __restrict__ bk,
    const int* __restrict__ idx,
    float* __restrict__ e_out, float* __restrict__ segsum,
    int n, int nt)
{
    extern __shared__ char smem[];   // 64 KB: BF staging (prologue) then X tile

    const int tid = threadIdx.x;
    const int w  = tid >> 6, l = tid & 63;
    const int lr = l & 15,  lg = l >> 4;

    // contiguous tile range for this block
    const int nb = gridDim.x, bx = blockIdx.x;
    const int qt = nt / nb, rt = nt % nb;
    const int t0  = bx * qt + (bx < rt ? bx : rt);
    const int ntb = qt + (bx < rt ? 1 : 0);
    if (ntb <= 0) return;

    // ---- phase 0: stage packed B fragments into LDS (r3-validated layout),
    //      then copy to VGPRs; LDS region is reused for X tiles afterwards.
    {
        _Float16* BF = (_Float16*)smem;
        const int ks = tid >> 5, lg2 = (tid >> 3) & 3, j = tid & 7;
        const float4* wqr = (const float4*)(Wq + (size_t)tid * HID);
        const float4* wkr = (const float4*)(Wk + (size_t)tid * HID);
#pragma unroll
        for (int i = 0; i < 8; ++i) {
            float4 vq = wqr[i];
            float4 vk = wkr[i];
            float fq[4] = { vq.x, vq.y, vq.z, vq.w };
            float fk[4] = { vk.x, vk.y, vk.z, vk.w };
#pragma unroll
            for (int u2 = 0; u2 < 4; ++u2) {
                int c = i * 4 + u2, cg = c >> 4, cr = c & 15;
                BF[(((cg    ) * 8 + ks) * 64 + lg2 * 16 + cr) * 8 + j] = (_Float16)fq[u2];
                BF[(((cg + 2) * 8 + ks) * 64 + lg2 * 16 + cr) * 8 + j] = (_Float16)fk[u2];
            }
        }
    }
    __syncthreads();
    half8 b[4][8];   // 128 VGPR: b[cg][ks], cg = {q0,q1,k0,k1}
    {
        const _Float16* bfl = (const _Float16*)smem + (size_t)l * 8;
#pragma unroll
        for (int cg = 0; cg < 4; ++cg)
#pragma unroll
            for (int ks = 0; ks < 8; ++ks)
                b[cg][ks] = *(const half8*)(bfl + (cg * 8 + ks) * 512);
    }
    __syncthreads();   // BF consumed; smem free for X staging

    const float bq0 = bq[lr], bq1 = bq[lr + 16];
    const float bk0 = bk[lr], bk1 = bk[lr + 16];

    // ---- stage helper: LDS linear, source pre-swizzled
    //      LDS[row][chunk c] = G[row][c ^ (row&7)]  (16B chunks)
    auto stage = [&](int ti) {
#pragma unroll
        for (int j = 0; j < 16; ++j) {
            const int row = j * 4 + w;                    // uniform per wave
            int grow = ti * TROWS + row;
            if (grow >= n) grow = n - 1;
            const float* src = x + (size_t)grow * IN_DIM + ((l ^ (row & 7)) << 2);
            gload_lds16(src, smem + row * ROWB);
        }
    };

    stage(t0);   // prologue

    for (int i = 0; i < ntb; ++i) {
        const int ti = t0 + i;

        __syncthreads();   // ONE drain: stage_i + epilogue_{i-1} (vmcnt(0))

        // ---- compute: wave w owns rows w*16 .. w*16+15
        floatx4 acc0 = {0.f,0.f,0.f,0.f}, acc1 = {0.f,0.f,0.f,0.f};
        floatx4 acc2 = {0.f,0.f,0.f,0.f}, acc3 = {0.f,0.f,0.f,0.f};
        const char* Xr = smem + (w * 16 + lr) * ROWB;
        const int sw = lr & 7;
#pragma unroll
        for (int ks = 0; ks < 8; ++ks) {
            float4 v0 = *(const float4*)(Xr + ks * 128 + (((lg * 2 + 0) ^ sw) << 4));
            float4 v1 = *(const float4*)(Xr + ks * 128 + (((lg * 2 + 1) ^ sw) << 4));
            union { half8 h8; fp16x2 h2[4]; } u;
            u.h2[0] = __builtin_amdgcn_cvt_pkrtz(v0.x, v0.y);
            u.h2[1] = __builtin_amdgcn_cvt_pkrtz(v0.z, v0.w);
            u.h2[2] = __builtin_amdgcn_cvt_pkrtz(v1.x, v1.y);
            u.h2[3] = __builtin_amdgcn_cvt_pkrtz(v1.z, v1.w);
            acc0 = __builtin_amdgcn_mfma_f32_16x16x32_f16(u.h8, b[0][ks], acc0, 0, 0, 0);
            acc1 = __builtin_amdgcn_mfma_f32_16x16x32_f16(u.h8, b[1][ks], acc1, 0, 0, 0);
            acc2 = __builtin_amdgcn_mfma_f32_16x16x32_f16(u.h8, b[2][ks], acc2, 0, 0, 0);
            acc3 = __builtin_amdgcn_mfma_f32_16x16x32_f16(u.h8, b[3][ks], acc3, 0, 0, 0);
        }

        // att = sum_h (qv+bq)*(kv+bk); reduce over 16 col-lanes (pure regs)
        float p[4];
#pragma unroll
        for (int i2 = 0; i2 < 4; ++i2) {
            p[i2] = (acc0[i2] + bq0) * (acc2[i2] + bk0)
                  + (acc1[i2] + bq1) * (acc3[i2] + bk1);
            p[i2] += __shfl_xor(p[i2], 1);
            p[i2] += __shfl_xor(p[i2], 2);
            p[i2] += __shfl_xor(p[i2], 4);
            p[i2] += __shfl_xor(p[i2], 8);
        }

        __syncthreads();   // LDS consumption complete (vmem already 0 -> cheap)

        if (i + 1 < ntb) stage(ti + 1);   // issue next stream FIRST

        // epilogue: fire-and-forget; drained together with stage at next top
        if (lr < 4) {   // 16 lanes each store one row
            float pv = (lr & 1) ? ((lr & 2) ? p[3] : p[1])
                                : ((lr & 2) ? p[2] : p[0]);
            int r = ti * TROWS + w * 16 + lg * 4 + lr;
            if (r < n) {
                float e = __expf(pv);   // no max-subtract: |att| small enough for f32
                e_out[r] = e;
                atomicAdd(&segsum[idx[r]], e);
            }
        }
    }
}

// out = e / segsum[idx], float4-vectorized
__global__ __launch_bounds__(256) void norm_kernel(
    const int* __restrict__ idx, const float* __restrict__ segsum,
    float* __restrict__ out, int n)
{
    int i = blockIdx.x * blockDim.x + threadIdx.x;
    int stride = gridDim.x * blockDim.x;
    int n4 = n >> 2;
    for (; i < n4; i += stride) {
        float4 e = ((const float4*)out)[i];
        int4  s4 = ((const int4*)idx)[i];
        float4 r;
        r.x = e.x / segsum[s4.x];
        r.y = e.y / segsum[s4.y];
        r.z = e.z / segsum[s4.z];
        r.w = e.w / segsum[s4.w];
        ((float4*)out)[i] = r;
    }
    if (blockIdx.x == 0 && threadIdx.x < (n & 3)) {
        int j = (n & ~3) + threadIdx.x;
        out[j] = out[j] / segsum[idx[j]];
    }
}

extern "C" void kernel_launch(void* const* d_in, const int* in_sizes, int n_in,
                              void* d_out, int out_size, void* d_ws, size_t ws_size,
                              hipStream_t stream)
{
    const float* x   = (const float*)d_in[0];
    const float* Wq  = (const float*)d_in[1];
    const float* bq  = (const float*)d_in[2];
    const float* Wk  = (const float*)d_in[3];
    const float* bk  = (const float*)d_in[4];
    const int*   idx = (const int*)d_in[5];
    const int n = in_sizes[5];

    float* segsum = (float*)d_ws;  // NSEG floats

    (void)hipMemsetAsync(segsum, 0, (size_t)NSEG * 4, stream);

    const int nt = (n + TROWS - 1) / TROWS;   // 64-row tiles
    int grid1 = 512;                          // 2 blocks/CU (64KB LDS each)
    if (grid1 > nt) grid1 = nt;
    att_kernel<<<grid1, 256, 65536, stream>>>(x, Wq, bq, Wk, bk, idx,
                                              (float*)d_out, segsum, n, nt);

    int n4 = n >> 2;
    int grid2 = (n4 + 255) / 256;
    if (grid2 > 1024) grid2 = 1024;
    if (grid2 < 1) grid2 = 1;
    norm_kernel<<<grid2, 256, 0, stream>>>(idx, segsum, (float*)d_out, n);
}

// Round 8
// 222.642 us; speedup vs baseline: 1.0449x; 1.0449x over previous
//
#include <hip/hip_runtime.h>
#include <hip/hip_fp16.h>
#include <math.h>

#define IN_DIM 256
#define HID 32
#define NSEG 100000
#define ROWB 1024     // bytes per x-row (256 f32)
#define WBUF 16384    // per-wave LDS buffer: 16 rows x 1KB

typedef _Float16 half8 __attribute__((ext_vector_type(8)));
typedef __fp16  fp16x2 __attribute__((ext_vector_type(2)));   // cvt_pkrtz return type
typedef float floatx4 __attribute__((ext_vector_type(4)));

// async global->LDS, 16B per lane, dest = wave-uniform base + lane*16 (m104)
__device__ __forceinline__ void gload_lds16(const float* g, char* l) {
    __builtin_amdgcn_global_load_lds(
        (const __attribute__((address_space(1))) void*)g,
        (__attribute__((address_space(3))) void*)l,
        16, 0, 0);
}

// Fused q/k projection (f16 MFMA, fp32 accum) + per-row dot + exp + segment-sum.
// BARRIER-FREE main loop: each wave owns a private 16KB LDS quarter and
// grid-strides over 16-row subtiles independently. Per-wave sync only:
//   s_waitcnt vmcnt(0)  before reading the LDS tile (own 16 loads done)
//   s_waitcnt lgkmcnt(0) before re-staging (own ds_reads done)
// 8 independent dephased waves/CU keep HBM demand continuous (no convoy).
__global__ __launch_bounds__(256, 2) void att_kernel(
    const float* __restrict__ x,
    const float* __restrict__ Wq, const float* __restrict__ bq,
    const float* __restrict__ Wk, const float* __restrict__ bk,
    const int* __restrict__ idx,
    float* __restrict__ e_out, float* __restrict__ segsum,
    int n, int nsub)
{
    extern __shared__ char smem[];   // 64 KB: BF staging (prologue) then 4x16KB wave buffers

    const int tid = threadIdx.x;
    const int w  = tid >> 6, l = tid & 63;
    const int lr = l & 15,  lg = l >> 4;

    // ---- phase 0 (block-wide, barriers ok): stage packed B fragments into LDS
    //      (r3-validated layout), copy to VGPRs, then LDS is repurposed.
    {
        _Float16* BF = (_Float16*)smem;
        const int ks = tid >> 5, lg2 = (tid >> 3) & 3, j = tid & 7;
        const float4* wqr = (const float4*)(Wq + (size_t)tid * HID);
        const float4* wkr = (const float4*)(Wk + (size_t)tid * HID);
#pragma unroll
        for (int i = 0; i < 8; ++i) {
            float4 vq = wqr[i];
            float4 vk = wkr[i];
            float fq[4] = { vq.x, vq.y, vq.z, vq.w };
            float fk[4] = { vk.x, vk.y, vk.z, vk.w };
#pragma unroll
            for (int u2 = 0; u2 < 4; ++u2) {
                int c = i * 4 + u2, cg = c >> 4, cr = c & 15;
                BF[(((cg    ) * 8 + ks) * 64 + lg2 * 16 + cr) * 8 + j] = (_Float16)fq[u2];
                BF[(((cg + 2) * 8 + ks) * 64 + lg2 * 16 + cr) * 8 + j] = (_Float16)fk[u2];
            }
        }
    }
    __syncthreads();
    half8 b[4][8];   // 128 VGPR: b[cg][ks], cg = {q0,q1,k0,k1}
    {
        const _Float16* bfl = (const _Float16*)smem + (size_t)l * 8;
#pragma unroll
        for (int cg = 0; cg < 4; ++cg)
#pragma unroll
            for (int ks = 0; ks < 8; ++ks)
                b[cg][ks] = *(const half8*)(bfl + (cg * 8 + ks) * 512);
    }
    __syncthreads();   // BF consumed; smem free for per-wave X buffers

    const float bq0 = bq[lr], bq1 = bq[lr + 16];
    const float bk0 = bk[lr], bk1 = bk[lr + 16];

    char* const Xw = smem + w * WBUF;          // this wave's private buffer
    const char* const Xr = Xw + lr * ROWB;     // this lane's row base
    const int sw = lr & 7;

    // stage subtile s into Xw: LDS linear, source pre-swizzled
    //   LDS[r][chunk c] = G[row][c ^ (r&7)]  (16B chunks)
    auto stage = [&](int s) {
#pragma unroll
        for (int r = 0; r < 16; ++r) {
            int grow = s * 16 + r;
            if (grow >= n) grow = n - 1;
            const float* src = x + (size_t)grow * IN_DIM + ((l ^ (r & 7)) << 2);
            gload_lds16(src, Xw + r * ROWB);
        }
    };

    const int gw      = blockIdx.x * 4 + w;
    const int gstride = gridDim.x * 4;

    int s = gw;
    if (s >= nsub) return;   // after both barriers: safe

    stage(s);

    while (true) {
        // own 16 loads (+ last iter's stores/atomics) complete
        asm volatile("s_waitcnt vmcnt(0)" ::: "memory");
        __builtin_amdgcn_sched_barrier(0);

        // ---- compute: lane's A-row = subtile row lr
        floatx4 acc0 = {0.f,0.f,0.f,0.f}, acc1 = {0.f,0.f,0.f,0.f};
        floatx4 acc2 = {0.f,0.f,0.f,0.f}, acc3 = {0.f,0.f,0.f,0.f};
#pragma unroll
        for (int ks = 0; ks < 8; ++ks) {
            float4 v0 = *(const float4*)(Xr + ks * 128 + (((lg * 2 + 0) ^ sw) << 4));
            float4 v1 = *(const float4*)(Xr + ks * 128 + (((lg * 2 + 1) ^ sw) << 4));
            union { half8 h8; fp16x2 h2[4]; } u;
            u.h2[0] = __builtin_amdgcn_cvt_pkrtz(v0.x, v0.y);
            u.h2[1] = __builtin_amdgcn_cvt_pkrtz(v0.z, v0.w);
            u.h2[2] = __builtin_amdgcn_cvt_pkrtz(v1.x, v1.y);
            u.h2[3] = __builtin_amdgcn_cvt_pkrtz(v1.z, v1.w);
            acc0 = __builtin_amdgcn_mfma_f32_16x16x32_f16(u.h8, b[0][ks], acc0, 0, 0, 0);
            acc1 = __builtin_amdgcn_mfma_f32_16x16x32_f16(u.h8, b[1][ks], acc1, 0, 0, 0);
            acc2 = __builtin_amdgcn_mfma_f32_16x16x32_f16(u.h8, b[2][ks], acc2, 0, 0, 0);
            acc3 = __builtin_amdgcn_mfma_f32_16x16x32_f16(u.h8, b[3][ks], acc3, 0, 0, 0);
        }

        // att = sum_h (qv+bq)*(kv+bk); reduce over the 16 col-lanes
        float p[4];
#pragma unroll
        for (int i2 = 0; i2 < 4; ++i2) {
            p[i2] = (acc0[i2] + bq0) * (acc2[i2] + bk0)
                  + (acc1[i2] + bq1) * (acc3[i2] + bk1);
            p[i2] += __shfl_xor(p[i2], 1);
            p[i2] += __shfl_xor(p[i2], 2);
            p[i2] += __shfl_xor(p[i2], 4);
            p[i2] += __shfl_xor(p[i2], 8);
        }

        const int snext = s + gstride;

        // all own ds_reads (incl. shfl ds-ops) retired -> safe to overwrite buffer
        asm volatile("s_waitcnt lgkmcnt(0)" ::: "memory");
        __builtin_amdgcn_sched_barrier(0);

        if (snext < nsub) stage(snext);   // issue next stream FIRST

        // epilogue: fire-and-forget; drained by next vmcnt(0)
        if (lr < 4) {   // 16 lanes each store one row: r = s*16 + lg*4 + lr
            float pv = (lr & 1) ? ((lr & 2) ? p[3] : p[1])
                                : ((lr & 2) ? p[2] : p[0]);
            int r = s * 16 + lg * 4 + lr;
            if (r < n) {
                float e = __expf(pv);   // no max-subtract: |att| small enough for f32
                e_out[r] = e;
                atomicAdd(&segsum[idx[r]], e);
            }
        }

        if (snext >= nsub) break;
        s = snext;
    }
}

// out = e / segsum[idx], float4-vectorized
__global__ __launch_bounds__(256) void norm_kernel(
    const int* __restrict__ idx, const float* __restrict__ segsum,
    float* __restrict__ out, int n)
{
    int i = blockIdx.x * blockDim.x + threadIdx.x;
    int stride = gridDim.x * blockDim.x;
    int n4 = n >> 2;
    for (; i < n4; i += stride) {
        float4 e = ((const float4*)out)[i];
        int4  s4 = ((const int4*)idx)[i];
        float4 r;
        r.x = e.x / segsum[s4.x];
        r.y = e.y / segsum[s4.y];
        r.z = e.z / segsum[s4.z];
        r.w = e.w / segsum[s4.w];
        ((float4*)out)[i] = r;
    }
    if (blockIdx.x == 0 && threadIdx.x < (n & 3)) {
        int j = (n & ~3) + threadIdx.x;
        out[j] = out[j] / segsum[idx[j]];
    }
}

extern "C" void kernel_launch(void* const* d_in, const int* in_sizes, int n_in,
                              void* d_out, int out_size, void* d_ws, size_t ws_size,
                              hipStream_t stream)
{
    const float* x   = (const float*)d_in[0];
    const float* Wq  = (const float*)d_in[1];
    const float* bq  = (const float*)d_in[2];
    const float* Wk  = (const float*)d_in[3];
    const float* bk  = (const float*)d_in[4];
    const int*   idx = (const int*)d_in[5];
    const int n = in_sizes[5];

    float* segsum = (float*)d_ws;  // NSEG floats

    (void)hipMemsetAsync(segsum, 0, (size_t)NSEG * 4, stream);

    const int nsub = (n + 15) >> 4;           // 16-row subtiles
    int grid1 = 512;                          // 2 blocks/CU (64KB LDS each), 2048 waves
    if (grid1 * 4 > nsub) grid1 = (nsub + 3) / 4;
    att_kernel<<<grid1, 256, 65536, stream>>>(x, Wq, bq, Wk, bk, idx,
                                              (float*)d_out, segsum, n, nsub);

    int n4 = n >> 2;
    int grid2 = (n4 + 255) / 256;
    if (grid2 > 1024) grid2 = 1024;
    if (grid2 < 1) grid2 = 1;
    norm_kernel<<<grid2, 256, 0, stream>>>(idx, segsum, (float*)d_out, n);
}